// Round 7
// baseline (295.092 us; speedup 1.0000x reference)
//
#include <hip/hip_runtime.h>
#include <math.h>

#define CDIV(a,b) (((a)+(b)-1)/(b))

// ---------- deg[dst]++ (int histogram) ----------
__global__ __launch_bounds__(256) void deg_kernel(
    const int* __restrict__ dst, int E, int* __restrict__ deg)
{
    int e = blockIdx.x * 256 + threadIdx.x;
    if (e >= E) return;
    atomicAdd(&deg[dst[e]], 1);
}

__global__ __launch_bounds__(256) void dinv_kernel(
    const int* __restrict__ deg, float* __restrict__ dinv, int N)
{
    int i = blockIdx.x * 256 + threadIdx.x;
    if (i >= N) return;
    dinv[i] = 1.0f / sqrtf((float)deg[i] + 1.0f);  // +1 for self-loop
}

// ---------- hierarchical exclusive scan ----------
__global__ __launch_bounds__(1024) void block_scan_kernel(
    const int* __restrict__ deg, int* __restrict__ excl,
    int* __restrict__ bsums, int N)
{
    __shared__ int buf[1024];
    const int t = threadIdx.x;
    const int i = blockIdx.x * 1024 + t;
    int v = (i < N) ? deg[i] : 0;
    buf[t] = v;
    __syncthreads();
    for (int offs = 1; offs < 1024; offs <<= 1) {
        int add = (t >= offs) ? buf[t - offs] : 0;
        __syncthreads();
        buf[t] += add;
        __syncthreads();
    }
    if (i < N) excl[i] = buf[t] - v;
    if (t == 1023) bsums[blockIdx.x] = buf[t];
}

__global__ __launch_bounds__(1024) void scan_bsums_kernel(
    int* __restrict__ bsums, int nb)
{
    __shared__ int buf[1024];
    const int t = threadIdx.x;
    int v = (t < nb) ? bsums[t] : 0;
    buf[t] = v;
    __syncthreads();
    for (int offs = 1; offs < 1024; offs <<= 1) {
        int add = (t >= offs) ? buf[t - offs] : 0;
        __syncthreads();
        buf[t] += add;
        __syncthreads();
    }
    if (t < nb) bsums[t] = buf[t] - v;  // exclusive
}

__global__ __launch_bounds__(256) void add_offsets_kernel(
    int* __restrict__ rowptr, int* __restrict__ cursor,
    const int* __restrict__ bsums, int N, int E)
{
    int i = blockIdx.x * 256 + threadIdx.x;
    if (i < N) {
        int v = rowptr[i] + bsums[i >> 10];
        rowptr[i] = v;
        cursor[i] = v;
    }
    if (i == N) rowptr[N] = E;
}

// ---------- scatter edges into CSR slots ----------
__global__ __launch_bounds__(256) void csr_build_kernel(
    const int* __restrict__ src, const int* __restrict__ dst,
    int* __restrict__ cursor, int* __restrict__ csr_src, int E)
{
    int e = blockIdx.x * 256 + threadIdx.x;
    if (e >= E) return;
    int pos = atomicAdd(&cursor[dst[e]], 1);
    csr_src[pos] = src[e];
}

// ---------- GEMM: tmp = A@W ----------
// W (col-slice) staged in LDS ONCE, single barrier, then barrier-free k-loop.
template<int FI, int FO, int COLS, int ROWS>
__global__ __launch_bounds__(256, 4) void gemm_kernel(
    const float* __restrict__ A, const float* __restrict__ W,
    float* __restrict__ tmp, int N)
{
    constexpr int NCB = FO / COLS;    // col-blocks
    constexpr int CT  = COLS / 4;     // col-threads (float4 each)
    constexpr int RT  = 256 / CT;     // row-threads
    constexpr int RPT = ROWS / RT;    // rows per thread

    __shared__ float sW[FI][COLS];

    const int t    = threadIdx.x;
    const int colb = (NCB > 1) ? (blockIdx.x % NCB) : 0;
    const int rowb = (NCB > 1) ? (blockIdx.x / NCB) : blockIdx.x;

    #pragma unroll
    for (int it = 0; it < (FI * COLS / 4) / 256; ++it) {
        int idx = it * 256 + t;
        int k   = idx / CT;
        int cq  = idx % CT;
        *reinterpret_cast<float4*>(&sW[k][cq * 4]) =
            *reinterpret_cast<const float4*>(W + (size_t)k * FO + colb * COLS + cq * 4);
    }
    __syncthreads();

    const int c0 = (t % CT) * 4;
    const int r0 = t / CT;

    const float* aptr[RPT];
    #pragma unroll
    for (int rr = 0; rr < RPT; ++rr) {
        int row = rowb * ROWS + r0 + rr * RT;
        int rc  = (row < N) ? row : (N - 1);   // clamp loads, guard stores
        aptr[rr] = A + (size_t)rc * FI;
    }

    float acc[RPT][4];
    #pragma unroll
    for (int rr = 0; rr < RPT; ++rr)
        #pragma unroll
        for (int c = 0; c < 4; ++c) acc[rr][c] = 0.0f;

    #pragma unroll 8
    for (int k4 = 0; k4 < FI / 4; ++k4) {
        float4 w0 = *reinterpret_cast<const float4*>(&sW[k4 * 4 + 0][c0]);
        float4 w1 = *reinterpret_cast<const float4*>(&sW[k4 * 4 + 1][c0]);
        float4 w2 = *reinterpret_cast<const float4*>(&sW[k4 * 4 + 2][c0]);
        float4 w3 = *reinterpret_cast<const float4*>(&sW[k4 * 4 + 3][c0]);
        #pragma unroll
        for (int rr = 0; rr < RPT; ++rr) {
            float4 a = *reinterpret_cast<const float4*>(aptr[rr] + k4 * 4);
            acc[rr][0] += a.x * w0.x + a.y * w1.x + a.z * w2.x + a.w * w3.x;
            acc[rr][1] += a.x * w0.y + a.y * w1.y + a.z * w2.y + a.w * w3.y;
            acc[rr][2] += a.x * w0.z + a.y * w1.z + a.z * w2.z + a.w * w3.z;
            acc[rr][3] += a.x * w0.w + a.y * w1.w + a.z * w2.w + a.w * w3.w;
        }
    }

    #pragma unroll
    for (int rr = 0; rr < RPT; ++rr) {
        int row = rowb * ROWS + r0 + rr * RT;
        if (row >= N) continue;
        *reinterpret_cast<float4*>(tmp + (size_t)row * FO + colb * COLS + c0) =
            make_float4(acc[rr][0], acc[rr][1], acc[rr][2], acc[rr][3]);
    }
}

// ---------- gather-side aggregation, multi-edge waves ----------
// One node per wave. Lanes split into EW=64*4/FO edge-slots of GL=FO/4 lanes;
// each lane loads float4. U-deep unroll => EW*U independent gather chains.
// Cross-slot __shfl_xor reduction at the end; then self-loop+bias+ReLU
// (+ fused final linear for the last layer).
template<int FO, bool RELU, bool FINAL>
__global__ __launch_bounds__(256) void agg_kernel(
    const int* __restrict__ rowptr, const int* __restrict__ csr_src,
    const float* __restrict__ dinv, const float* __restrict__ tmp,
    const float* __restrict__ b, float* __restrict__ h,
    const float* __restrict__ Wl, const float* __restrict__ bl,
    float* __restrict__ out, int N)
{
    constexpr int GL = FO / 4;        // lanes per edge-slot
    constexpr int EW = 64 / GL;       // edge-slots per wave
    constexpr int U  = (FO == 32) ? 2 : 4;
    const int wid  = (blockIdx.x * 256 + threadIdx.x) >> 6;
    const int lane = threadIdx.x & 63;
    const int g    = lane / GL;       // edge slot
    const int f    = lane % GL;       // float4 index within row
    const int node = wid;
    if (node >= N) return;

    const float dvd = dinv[node];
    const int jb = rowptr[node], je = rowptr[node + 1];

    float4 acc[U];
    #pragma unroll
    for (int u = 0; u < U; ++u) acc[u] = make_float4(0.f, 0.f, 0.f, 0.f);

    for (int j0 = jb; j0 < je; j0 += EW * U) {
        #pragma unroll
        for (int u = 0; u < U; ++u) {
            int jj = j0 + u * EW + g;
            if (jj < je) {
                int s = csr_src[jj];
                float w = dinv[s] * dvd;
                float4 v = *reinterpret_cast<const float4*>(tmp + (size_t)s * FO + f * 4);
                acc[u].x += v.x * w; acc[u].y += v.y * w;
                acc[u].z += v.z * w; acc[u].w += v.w * w;
            }
        }
    }
    float4 a = acc[0];
    #pragma unroll
    for (int u = 1; u < U; ++u) {
        a.x += acc[u].x; a.y += acc[u].y; a.z += acc[u].z; a.w += acc[u].w;
    }
    // cross-slot reduction: all lanes end with the full edge sum for their f
    #pragma unroll
    for (int m = GL; m < 64; m <<= 1) {
        a.x += __shfl_xor(a.x, m, 64);
        a.y += __shfl_xor(a.y, m, 64);
        a.z += __shfl_xor(a.z, m, 64);
        a.w += __shfl_xor(a.w, m, 64);
    }
    // self-loop + bias (+ReLU), uniform across lanes
    const float d2 = dvd * dvd;
    float4 sv = *reinterpret_cast<const float4*>(tmp + (size_t)node * FO + f * 4);
    const float4 bb = *reinterpret_cast<const float4*>(b + f * 4);
    a.x = a.x + sv.x * d2 + bb.x;
    a.y = a.y + sv.y * d2 + bb.y;
    a.z = a.z + sv.z * d2 + bb.z;
    a.w = a.w + sv.w * d2 + bb.w;
    if (RELU) {
        a.x = fmaxf(a.x, 0.f); a.y = fmaxf(a.y, 0.f);
        a.z = fmaxf(a.z, 0.f); a.w = fmaxf(a.w, 0.f);
    }

    if (FINAL) {
        const float4 wl = *reinterpret_cast<const float4*>(Wl + f * 4);
        float r = a.x * wl.x + a.y * wl.y + a.z * wl.z + a.w * wl.w;
        #pragma unroll
        for (int m = 1; m < GL; m <<= 1)
            r += __shfl_xor(r, m, 64);
        if (lane == 0) out[node] = r + bl[0];
    } else if (g == 0) {
        *reinterpret_cast<float4*>(h + (size_t)node * FO + f * 4) = a;
    }
}

extern "C" void kernel_launch(void* const* d_in, const int* in_sizes, int n_in,
                              void* d_out, int out_size, void* d_ws, size_t ws_size,
                              hipStream_t stream)
{
    const float* x  = (const float*)d_in[0];
    const int*   ei = (const int*)d_in[1];   // int inputs arrive as int32
    const float* W1 = (const float*)d_in[2];
    const float* b1 = (const float*)d_in[3];
    const float* W2 = (const float*)d_in[4];
    const float* b2 = (const float*)d_in[5];
    const float* W3 = (const float*)d_in[6];
    const float* b3 = (const float*)d_in[7];
    const float* Wl = (const float*)d_in[8];
    const float* bl = (const float*)d_in[9];
    float* out = (float*)d_out;

    const int N = in_sizes[0] / 128;
    const int E = in_sizes[1] / 2;

    const int* src = ei;        // edge_index row 0
    const int* dst = ei + E;    // edge_index row 1

    char* ws = (char*)d_ws;
    size_t off = 0;
    auto wsalloc = [&](size_t bytes) -> void* {
        void* p = ws + off;
        off = (off + bytes + 255) & ~(size_t)255;
        return p;
    };
    const int NB = CDIV(N, 1024);
    int*   deg     = (int*)  wsalloc((size_t)N * 4);
    float* dinv    = (float*)wsalloc((size_t)N * 4);
    int*   rowptr  = (int*)  wsalloc((size_t)(N + 1) * 4);
    int*   cursor  = (int*)  wsalloc((size_t)N * 4);
    int*   bsums   = (int*)  wsalloc((size_t)NB * 4);
    int*   csr_src = (int*)  wsalloc((size_t)E * 4);
    float* B1      = (float*)wsalloc((size_t)N * 128 * 4);  // tmp
    float* B2      = (float*)wsalloc((size_t)N * 128 * 4);  // h
    // total ws use: ~55 MB

    // ---- CSR build ----
    hipMemsetAsync(deg, 0, (size_t)N * 4, stream);
    deg_kernel<<<CDIV(E, 256), 256, 0, stream>>>(dst, E, deg);
    dinv_kernel<<<CDIV(N, 256), 256, 0, stream>>>(deg, dinv, N);
    block_scan_kernel<<<NB, 1024, 0, stream>>>(deg, rowptr, bsums, N);
    scan_bsums_kernel<<<1, 1024, 0, stream>>>(bsums, NB);
    add_offsets_kernel<<<CDIV(N + 1, 256), 256, 0, stream>>>(rowptr, cursor, bsums, N, E);
    csr_build_kernel<<<CDIV(E, 256), 256, 0, stream>>>(src, dst, cursor, csr_src, E);

    // ---- layer 1: 128 -> 128 (col-split x2) ----
    gemm_kernel<128, 128, 64, 64><<<2 * CDIV(N, 64), 256, 0, stream>>>(x, W1, B1, N);
    agg_kernel<128, true, false><<<CDIV(N, 4), 256, 0, stream>>>(
        rowptr, csr_src, dinv, B1, b1, B2, nullptr, nullptr, nullptr, N);

    // ---- layer 2: 128 -> 64 ----
    gemm_kernel<128, 64, 64, 64><<<CDIV(N, 64), 256, 0, stream>>>(B2, W2, B1, N);
    agg_kernel<64, true, false><<<CDIV(N, 4), 256, 0, stream>>>(
        rowptr, csr_src, dinv, B1, b2, B2, nullptr, nullptr, nullptr, N);

    // ---- layer 3: 64 -> 32, final linear fused into agg ----
    gemm_kernel<64, 32, 32, 64><<<CDIV(N, 64), 256, 0, stream>>>(B2, W3, B1, N);
    agg_kernel<32, true, true><<<CDIV(N, 4), 256, 0, stream>>>(
        rowptr, csr_src, dinv, B1, b3, nullptr, Wl, bl, out, N);
}